// Round 8
// baseline (57.627 us; speedup 1.0000x reference)
//
#include <hip/hip_runtime.h>

#define HW 224
#define CHW (HW*HW)

__global__ __launch_bounds__(256) void patch_conv_kernel(
    const float* __restrict__ X,    // [B][3][224][224]
    const float* __restrict__ Wt,   // [3][3][3][3] OIHW
    const float* __restrict__ Bv,   // [3]
    const float* __restrict__ P,    // [3136][48]
    float* __restrict__ out)        // [B][196][768]
{
    const int tid  = threadIdx.x;
    const int lane = tid & 63;
    const int wv   = tid >> 6;
    const int r    = lane >> 4;              // 0..3 (row within wave)
    const int c    = lane & 15;              // 0..15 (16-px column group)
    const int b    = blockIdx.y;
    const int y    = blockIdx.x * 16 + wv * 4 + r;   // 0..223
    const int x0   = c * 16;
    if (c >= 14) return;                     // 56/64 lanes active; no barriers

    // ---- weights: wave-uniform -> scalar loads / SGPRs
    float w[81];
    #pragma unroll
    for (int i = 0; i < 81; ++i) w[i] = Wt[i];

    // ---- acc init: bias + position embedding (P is L2-resident, 12 indep loads)
    float acc[3][16];
    const int nf0 = (y >> 2) * 56 + c * 4;   // first of 4 fine patches
    const int sub = (y & 3) * 4;
    #pragma unroll
    for (int co = 0; co < 3; ++co) {
        const float bb = Bv[co];
        #pragma unroll
        for (int q = 0; q < 4; ++q) {
            const float4 p = *(const float4*)(P + (nf0 + q) * 48 + co * 16 + sub);
            acc[co][q * 4 + 0] = bb + p.x;
            acc[co][q * 4 + 1] = bb + p.y;
            acc[co][q * 4 + 2] = bb + p.z;
            acc[co][q * 4 + 3] = bb + p.w;
        }
    }

    const float* Xb = X + (size_t)b * (3 * CHW);

    // ---- 9 windows of 18 floats each; 4 float4 + 2 edge scalars per window
    #pragma unroll
    for (int ci = 0; ci < 3; ++ci) {
        #pragma unroll
        for (int ky = 0; ky < 3; ++ky) {
            const int ry = y - 1 + ky;
            float win[18];
            if ((unsigned)ry < HW) {          // divergent only at image top/bottom
                const float* row = Xb + ci * CHW + ry * HW;
                const float4 v0 = *(const float4*)(row + x0);
                const float4 v1 = *(const float4*)(row + x0 + 4);
                const float4 v2 = *(const float4*)(row + x0 + 8);
                const float4 v3 = *(const float4*)(row + x0 + 12);
                win[0]  = (x0 > 0) ? row[x0 - 1] : 0.f;
                win[1]  = v0.x; win[2]  = v0.y; win[3]  = v0.z; win[4]  = v0.w;
                win[5]  = v1.x; win[6]  = v1.y; win[7]  = v1.z; win[8]  = v1.w;
                win[9]  = v2.x; win[10] = v2.y; win[11] = v2.z; win[12] = v2.w;
                win[13] = v3.x; win[14] = v3.y; win[15] = v3.z; win[16] = v3.w;
                win[17] = (x0 + 16 < HW) ? row[x0 + 16] : 0.f;
            } else {
                #pragma unroll
                for (int j = 0; j < 18; ++j) win[j] = 0.f;
            }
            #pragma unroll
            for (int co = 0; co < 3; ++co) {
                const float w0 = w[((co * 3 + ci) * 3 + ky) * 3 + 0];
                const float w1 = w[((co * 3 + ci) * 3 + ky) * 3 + 1];
                const float w2 = w[((co * 3 + ci) * 3 + ky) * 3 + 2];
                #pragma unroll
                for (int j = 0; j < 16; ++j)
                    acc[co][j] += w0 * win[j] + w1 * win[j + 1] + w2 * win[j + 2];
            }
        }
    }

    // ---- store: thread owns a full 16-px row of one coarse patch, per co
    const int nc = (y >> 4) * 14 + c;
    float* op = out + (size_t)b * (196 * 768) + nc * 768 + (y & 15) * 16;
    #pragma unroll
    for (int co = 0; co < 3; ++co)
        #pragma unroll
        for (int q = 0; q < 4; ++q)
            *(float4*)(op + co * 256 + q * 4) =
                make_float4(acc[co][q * 4 + 0], acc[co][q * 4 + 1],
                            acc[co][q * 4 + 2], acc[co][q * 4 + 3]);
}

extern "C" void kernel_launch(void* const* d_in, const int* in_sizes, int n_in,
                              void* d_out, int out_size, void* d_ws, size_t ws_size,
                              hipStream_t stream) {
    const float* X  = (const float*)d_in[0];
    const float* Wt = (const float*)d_in[1];
    const float* Bv = (const float*)d_in[2];
    const float* P  = (const float*)d_in[3];
    float* out = (float*)d_out;

    // block = 16 image rows (one coarse patch row); 14 x-blocks x 128 images
    dim3 grid(14, 128);
    patch_conv_kernel<<<grid, 256, 0, stream>>>(X, Wt, Bv, P, out);
}

// Round 9
// 39.367 us; speedup vs baseline: 1.4638x; 1.4638x over previous
//
#include <hip/hip_runtime.h>

#define HW 224
#define CHW (HW*HW)

__global__ __launch_bounds__(256) void patch_conv_kernel(
    const float* __restrict__ X,    // [B][3][224][224]
    const float* __restrict__ Wt,   // [3][3][3][3] OIHW
    const float* __restrict__ Bv,   // [3]
    const float* __restrict__ P,    // [3136][48]
    float* __restrict__ out)        // [B][196][768]
{
    const int tid  = threadIdx.x;
    const int lane = tid & 63;
    const int wv   = tid >> 6;
    const int b    = blockIdx.y;
    const int y0   = blockIdx.x * 8 + wv * 2;   // even; wave owns rows y0, y0+1
    const int x0   = lane * 4;                  // 0..252
    const bool act = (x0 < HW);                 // lanes 56..63 assist shfl only

    // ---- weights: wave-uniform -> SGPRs
    float w[81];
    #pragma unroll
    for (int i = 0; i < 81; ++i) w[i] = Wt[i];

    const float* Xb = X + (size_t)b * (3 * CHW);

    // ---- issue ALL 12 X loads up-front (rows y0-1..y0+2 x 3 channels)
    float4 v[3][4];
    #pragma unroll
    for (int ci = 0; ci < 3; ++ci) {
        #pragma unroll
        for (int rj = 0; rj < 4; ++rj) {
            const int ry = y0 - 1 + rj;
            float4 t = make_float4(0.f, 0.f, 0.f, 0.f);
            if ((unsigned)ry < HW && act)
                t = *(const float4*)(Xb + ci * CHW + ry * HW + x0);
            v[ci][rj] = t;
        }
    }

    // ---- 6 P loads, also up-front (rows y0,y0+1 are always in the SAME fine
    // row since y0 is even: nf identical, sub differs by 4)
    const int nf   = (y0 >> 2) * 56 + lane;     // lane == x0>>2
    const int sub0 = (y0 & 3) * 4;              // 0 or 8
    float4 pr[2][3];
    #pragma unroll
    for (int rr = 0; rr < 2; ++rr) {
        #pragma unroll
        for (int co = 0; co < 3; ++co) {
            float4 t = make_float4(0.f, 0.f, 0.f, 0.f);
            if (act)
                t = *(const float4*)(P + nf * 48 + co * 16 + sub0 + rr * 4);
            pr[rr][co] = t;
        }
    }

    // ---- edges via shfl (all 64 lanes participate)
    float win[3][4][6];
    #pragma unroll
    for (int ci = 0; ci < 3; ++ci) {
        #pragma unroll
        for (int rj = 0; rj < 4; ++rj) {
            float lf = __shfl_up(v[ci][rj].w, 1);
            float rt = __shfl_down(v[ci][rj].x, 1);
            if (lane == 0) lf = 0.f;
            if (x0 + 4 >= HW) rt = 0.f;
            win[ci][rj][0] = lf;
            win[ci][rj][1] = v[ci][rj].x; win[ci][rj][2] = v[ci][rj].y;
            win[ci][rj][3] = v[ci][rj].z; win[ci][rj][4] = v[ci][rj].w;
            win[ci][rj][5] = rt;
        }
    }

    if (!act) return;

    // ---- accumulators: bias + P
    float acc[2][3][4];
    #pragma unroll
    for (int rr = 0; rr < 2; ++rr) {
        #pragma unroll
        for (int co = 0; co < 3; ++co) {
            const float bb = Bv[co];
            acc[rr][co][0] = bb + pr[rr][co].x;
            acc[rr][co][1] = bb + pr[rr][co].y;
            acc[rr][co][2] = bb + pr[rr][co].z;
            acc[rr][co][3] = bb + pr[rr][co].w;
        }
    }

    // ---- 648 FMAs: row0 uses win[.][ky], row1 uses win[.][ky+1]
    #pragma unroll
    for (int ci = 0; ci < 3; ++ci) {
        #pragma unroll
        for (int ky = 0; ky < 3; ++ky) {
            const float* r0 = win[ci][ky];
            const float* r1 = win[ci][ky + 1];
            #pragma unroll
            for (int co = 0; co < 3; ++co) {
                const float w0 = w[((co * 3 + ci) * 3 + ky) * 3 + 0];
                const float w1 = w[((co * 3 + ci) * 3 + ky) * 3 + 1];
                const float w2 = w[((co * 3 + ci) * 3 + ky) * 3 + 2];
                #pragma unroll
                for (int j = 0; j < 4; ++j) {
                    acc[0][co][j] += w0 * r0[j] + w1 * r0[j + 1] + w2 * r0[j + 2];
                    acc[1][co][j] += w0 * r1[j] + w1 * r1[j + 1] + w2 * r1[j + 2];
                }
            }
        }
    }

    // ---- stores: both rows share the same coarse patch (y0 even)
    const int nc = (y0 >> 4) * 14 + (x0 >> 4);
    float* opb = out + (size_t)b * (196 * 768) + nc * 768 + (x0 & 15);
    #pragma unroll
    for (int rr = 0; rr < 2; ++rr) {
        float* op = opb + ((y0 + rr) & 15) * 16;
        #pragma unroll
        for (int co = 0; co < 3; ++co)
            *(float4*)(op + co * 256) =
                make_float4(acc[rr][co][0], acc[rr][co][1],
                            acc[rr][co][2], acc[rr][co][3]);
    }
}

extern "C" void kernel_launch(void* const* d_in, const int* in_sizes, int n_in,
                              void* d_out, int out_size, void* d_ws, size_t ws_size,
                              hipStream_t stream) {
    const float* X  = (const float*)d_in[0];
    const float* Wt = (const float*)d_in[1];
    const float* Bv = (const float*)d_in[2];
    const float* P  = (const float*)d_in[3];
    float* out = (float*)d_out;

    // wave = 2 rows; block = 4 waves = 8 rows; 28 x-blocks x 128 images
    dim3 grid(28, 128);
    patch_conv_kernel<<<grid, 256, 0, stream>>>(X, Wt, Bv, P, out);
}